// Round 6
// baseline (4377.933 us; speedup 1.0000x reference)
//
#include <hip/hip_runtime.h>
#include <cstdint>
#include <cstddef>

// SNN pipeline, np-fp32-replication strategy (round 6):
//  k1: cur1 = x@W1+b1 as fp32 k-ascending FMA chains (OpenBLAS replica) + fp32-replica
//      LIF-1 -> packed 10-bit spike masks (unchanged, passing).
//  k2: spike GEMM, 2-plane Dekker f16 split of W2. Barrier-free: NO LDS — B fragments
//      read directly from global (L2-resident, line-efficient gather), A masks direct,
//      both 1-iter register-prefetched. Unpack = 2 VALU/dword: (ga << (10-t)) & 0x04000400
//      -> exact f16 {0, 2^-14} pair; 2^14 folded into the fp64 epilogue combine
//      (bit-identical to round-5 numerics). fp32-replica LIF-2, shfl Wo partials.
//  k3: sum 32 partials, fp32-replica LIF-out, mean -> d_out.
// ws: w2d 4MiB @0 | s1bits 128MiB @16MiB | po 80MiB @160MiB

typedef _Float16 f16;
typedef _Float16 f16x8 __attribute__((ext_vector_type(8)));
typedef float f32x4 __attribute__((ext_vector_type(4)));
typedef int i32x4 __attribute__((ext_vector_type(4)));

#define MFMA16(A, B, C) __builtin_amdgcn_mfma_f32_16x16x32_f16(A, B, C, 0, 0, 0)

static constexpr int BSZ = 65536;
static constexpr int IN = 512;
static constexpr int H = 1024;

// W2[k][j] fp32 -> w2d[plane][j][k] f16 Dekker limbs: plane0 = f16(w),
// plane1 = f16((w - hi) * 2^11).
__global__ void prep_dekker(const float* __restrict__ src, f16* __restrict__ dst) {
    int idx = blockIdx.x * 256 + threadIdx.x;
    int k = idx >> 10;
    int j = idx & 1023;
    float w = src[(size_t)k * 1024 + j];
    f16 hi = (f16)w;
    float lo = (w - (float)hi) * 2048.0f;
    size_t o = (size_t)j * 1024 + k;
    dst[o] = hi;
    dst[o + (size_t)H * H] = (f16)lo;
}

// k1: fp32 k-ordered FMA-chain GEMM (BLAS-replica) + fp32-replica LIF -> spike masks.
// tile 64 b-rows x 256 h-cols, 256 threads = 16 ht x 16 bt, thread = 4b x 16h.
__global__ __launch_bounds__(256, 2) void k1_chain(
    const float* __restrict__ x, const float* __restrict__ w1,
    const float* __restrict__ b1, unsigned short* __restrict__ s1b) {
    __shared__ float xs[32][65];    // [k][b] (+1 pad)
    __shared__ float ws[32][256];   // [k][h]
    const int hblk = blockIdx.x;    // 4
    const int bblk = blockIdx.y;    // 1024
    const int tid = threadIdx.x;
    const int ht = tid & 15, bt = tid >> 4;
    const int h0 = hblk * 256, b0 = bblk * 64;

    float acc[4][16] = {};

    for (int kc = 0; kc < 512; kc += 32) {
        float4 xv[2], wv[8];
#pragma unroll
        for (int i = 0; i < 2; ++i) {
            int idx = tid + 256 * i;            // 512 f4: 64 rows x 8 segs
            int br = idx >> 3, ks = idx & 7;
            xv[i] = *(const float4*)&x[(size_t)(b0 + br) * IN + kc + ks * 4];
        }
#pragma unroll
        for (int i = 0; i < 8; ++i) {
            int idx = tid + 256 * i;            // 2048 f4: 32 rows x 64 segs
            int kr = idx >> 6, c4 = idx & 63;
            wv[i] = *(const float4*)&w1[(size_t)(kc + kr) * H + h0 + c4 * 4];
        }
        __syncthreads();
#pragma unroll
        for (int i = 0; i < 2; ++i) {
            int idx = tid + 256 * i;
            int br = idx >> 3, ks = idx & 7;
            xs[ks * 4 + 0][br] = xv[i].x;
            xs[ks * 4 + 1][br] = xv[i].y;
            xs[ks * 4 + 2][br] = xv[i].z;
            xs[ks * 4 + 3][br] = xv[i].w;
        }
#pragma unroll
        for (int i = 0; i < 8; ++i) {
            int idx = tid + 256 * i;
            int kr = idx >> 6, c4 = idx & 63;
            *(float4*)&ws[kr][c4 * 4] = wv[i];
        }
        __syncthreads();
#pragma unroll
        for (int k = 0; k < 32; ++k) {
            float xr[4];
#pragma unroll
            for (int i = 0; i < 4; ++i) xr[i] = xs[k][bt * 4 + i];
            float wr[16];
#pragma unroll
            for (int g = 0; g < 4; ++g) {
                float4 t = *(const float4*)&ws[k][ht * 16 + g * 4];
                wr[g * 4 + 0] = t.x; wr[g * 4 + 1] = t.y;
                wr[g * 4 + 2] = t.z; wr[g * 4 + 3] = t.w;
            }
#pragma unroll
            for (int i = 0; i < 4; ++i)
#pragma unroll
                for (int j = 0; j < 16; ++j)
                    acc[i][j] = fmaf(xr[i], wr[j], acc[i][j]);  // strict k-order chain
        }
    }

    float b1v[16];
#pragma unroll
    for (int j = 0; j < 16; ++j) b1v[j] = b1[h0 + ht * 16 + j];
#pragma unroll
    for (int i = 0; i < 4; ++i) {
        unsigned short outb[16];
#pragma unroll
        for (int j = 0; j < 16; ++j) {
            float c = __fadd_rn(acc[i][j], b1v[j]);
            float m = 0.0f;
            unsigned bits = 0u;
#pragma unroll
            for (int t = 0; t < 10; ++t) {
                float rst = (m > 1.0f) ? 1.0f : 0.0f;
                m = __fmul_rn(0.9f, m);
                m = __fadd_rn(m, c);
                m = __fsub_rn(m, rst);
                if (m > 1.0f) bits |= (1u << t);
            }
            outb[j] = (unsigned short)bits;
        }
        size_t off = (size_t)(b0 + bt * 4 + i) * H + h0 + ht * 16;
        *(int4*)&s1b[off] = ((const int4*)outb)[0];
        *(int4*)&s1b[off + 8] = ((const int4*)outb)[1];
    }
}

// k2: barrier-free spike GEMM. Block = 64 rows x 32 cols; wave = 16 rows x 32 cols.
// A masks + B fragments direct from global with 1-iter register prefetch. No LDS.
__global__ __launch_bounds__(256, 2) void k2_spikes_gemm(
    const unsigned short* __restrict__ s1bits, const f16* __restrict__ w2d,
    const float* __restrict__ b2, const float* __restrict__ wo,
    float* __restrict__ po) {
    const int jblk = blockIdx.x, bblk = blockIdx.y;
    const int tid = threadIdx.x;
    const int lane = tid & 63, wave = tid >> 6;
    const int l15 = lane & 15, loct = lane >> 4;

    const unsigned short* asrc =
        s1bits + (size_t)(bblk * 64 + wave * 16 + l15) * 1024 + loct * 8;
    const f16* bbase = w2d + (size_t)(jblk * 32 + l15) * 1024 + loct * 8;
    const size_t PL = (size_t)H * H;      // plane stride
    const size_t CF = (size_t)16 * 1024;  // col-frag stride

    f32x4 acc[10][2][2] = {};   // [t][plane][colfrag]

    i32x4 ga = *(const i32x4*)asrc;
    f16x8 bf00 = *(const f16x8*)(bbase);
    f16x8 bf01 = *(const f16x8*)(bbase + CF);
    f16x8 bf10 = *(const f16x8*)(bbase + PL);
    f16x8 bf11 = *(const f16x8*)(bbase + PL + CF);

    for (int kc = 0; kc < 1024; kc += 32) {
        int kn = (kc + 32) & 1023;   // wraps to 0 on last iter (dummy prefetch)
        i32x4 ga_n = *(const i32x4*)(asrc + kn);
        f16x8 bn00 = *(const f16x8*)(bbase + kn);
        f16x8 bn01 = *(const f16x8*)(bbase + kn + CF);
        f16x8 bn10 = *(const f16x8*)(bbase + kn + PL);
        f16x8 bn11 = *(const f16x8*)(bbase + kn + PL + CF);
#pragma unroll
        for (int t = 0; t < 10; ++t) {
            union { i32x4 i; f16x8 h; } u;
#pragma unroll
            for (int q = 0; q < 4; ++q)
                u.i[q] = (int)(((unsigned)ga[q] << (10 - t)) & 0x04000400u);
            acc[t][0][0] = MFMA16(u.h, bf00, acc[t][0][0]);
            acc[t][0][1] = MFMA16(u.h, bf01, acc[t][0][1]);
            acc[t][1][0] = MFMA16(u.h, bf10, acc[t][1][0]);
            acc[t][1][1] = MFMA16(u.h, bf11, acc[t][1][1]);
        }
        ga = ga_n;
        bf00 = bn00; bf01 = bn01; bf10 = bn10; bf11 = bn11;
    }

    // epilogue: Dekker combine (x2^14 unpack scale folded in: 16384, 8),
    // fp32-replica LIF-2, in-wave Wo partial reduce.
    int col0 = jblk * 32 + l15;
    float b2v0 = b2[col0], b2v1 = b2[col0 + 16];
    double wov0 = (double)wo[col0], wov1 = (double)wo[col0 + 16];
    int rowb = bblk * 64 + wave * 16 + loct * 4;
    float m2a[4] = {0.0f, 0.0f, 0.0f, 0.0f};
    float m2b[4] = {0.0f, 0.0f, 0.0f, 0.0f};
#pragma unroll
    for (int t = 0; t < 10; ++t) {
#pragma unroll
        for (int r = 0; r < 4; ++r) {
            float i0 = (float)((double)acc[t][0][0][r] * 16384.0 + (double)acc[t][1][0][r] * 8.0);
            i0 = __fadd_rn(i0, b2v0);
            float rst0 = (m2a[r] > 1.0f) ? 1.0f : 0.0f;
            m2a[r] = __fmul_rn(0.9f, m2a[r]);
            m2a[r] = __fadd_rn(m2a[r], i0);
            m2a[r] = __fsub_rn(m2a[r], rst0);
            float i1 = (float)((double)acc[t][0][1][r] * 16384.0 + (double)acc[t][1][1][r] * 8.0);
            i1 = __fadd_rn(i1, b2v1);
            float rst1 = (m2b[r] > 1.0f) ? 1.0f : 0.0f;
            m2b[r] = __fmul_rn(0.9f, m2b[r]);
            m2b[r] = __fadd_rn(m2b[r], i1);
            m2b[r] = __fsub_rn(m2b[r], rst1);
            double pv = ((m2a[r] > 1.0f) ? wov0 : 0.0) + ((m2b[r] > 1.0f) ? wov1 : 0.0);
            pv += __shfl_xor(pv, 1);
            pv += __shfl_xor(pv, 2);
            pv += __shfl_xor(pv, 4);
            pv += __shfl_xor(pv, 8);
            if (l15 == r)
                po[(size_t)(t * 32 + jblk) * BSZ + rowb + r] = (float)pv;
        }
    }
}

// k3: sum 32 partials (ascending j-blocks), fp32-replica LIF-out, mean.
__global__ void k3_out(const float* __restrict__ po, const float* __restrict__ bo,
                       float* __restrict__ out) {
    int b = blockIdx.x * 256 + threadIdx.x;
    float mo = 0.0f, s = 0.0f;
    float bov = bo[0];
    for (int t = 0; t < 10; ++t) {
        float inp = 0.0f;
#pragma unroll
        for (int jb = 0; jb < 32; ++jb) inp += po[(size_t)(t * 32 + jb) * BSZ + b];
        inp = __fadd_rn(inp, bov);
        float rst = (mo > 1.0f) ? 1.0f : 0.0f;
        mo = __fmul_rn(0.9f, mo);
        mo = __fadd_rn(mo, inp);
        mo = __fsub_rn(mo, rst);
        s += mo;
    }
    out[b] = s / 10.0f;
}

extern "C" void kernel_launch(void* const* d_in, const int* in_sizes, int n_in,
                              void* d_out, int out_size, void* d_ws, size_t ws_size,
                              hipStream_t stream) {
    (void)in_sizes; (void)n_in; (void)out_size; (void)ws_size;
    const float* x  = (const float*)d_in[0];
    const float* W1 = (const float*)d_in[1];
    const float* b1 = (const float*)d_in[2];
    const float* W2 = (const float*)d_in[3];
    const float* b2 = (const float*)d_in[4];
    const float* Wo = (const float*)d_in[5];
    const float* bo = (const float*)d_in[6];
    float* out = (float*)d_out;

    char* ws = (char*)d_ws;
    f16* w2d = (f16*)ws;                                                   // 4 MiB @ 0
    unsigned short* s1bits = (unsigned short*)(ws + ((size_t)16 << 20));   // 128 MiB
    float* po = (float*)(ws + ((size_t)160 << 20));                        // 80 MiB

    prep_dekker<<<dim3((H * H) / 256), 256, 0, stream>>>(W2, w2d);
    k1_chain<<<dim3(4, BSZ / 64), 256, 0, stream>>>(x, W1, b1, s1bits);
    k2_spikes_gemm<<<dim3(H / 32, BSZ / 64), 256, 0, stream>>>(s1bits, w2d, b2, Wo, po);
    k3_out<<<dim3(BSZ / 256), 256, 0, stream>>>(po, bo, out);
}

// Round 7
// 3622.194 us; speedup vs baseline: 1.2086x; 1.2086x over previous
//
#include <hip/hip_runtime.h>
#include <cstdint>
#include <cstddef>

// SNN pipeline, np-fp32-replication strategy (round 7):
//  k1: cur1 = x@W1+b1 as fp32 k-ascending FMA chains (OpenBLAS replica) + fp32-replica
//      LIF-1 -> packed 10-bit spike masks (unchanged, passing).
//  k2: spike GEMM, 2-plane Dekker f16 split of W2. 512-thread blocks, 8 waves =
//      4 row-strips x 2 t-halves (t0-4 / t5-9): acc[5][2][2] = 80 VGPRs/wave ->
//      4 waves/SIMD (launch_bounds(512,4)) for 2x latency hiding vs round 5.
//      A masks AND B limbs staged via LDS (coalesced; round-6 direct gathers were
//      TA-transaction-bound), double-buffered, 1 barrier/iter, register prefetch.
//      Unpack = 2 VALU/dword: (mask << (10-t)) & 0x04000400 -> exact f16 {0,2^-14};
//      scale folded into fp64 epilogue combine. LIF-2 m2 handoff t4->t5 via LDS.
//  k3: sum 32 partials, fp32-replica LIF-out, mean -> d_out.
// ws: w2d 4MiB @0 | s1bits 128MiB @16MiB | po 80MiB @160MiB

typedef _Float16 f16;
typedef _Float16 f16x8 __attribute__((ext_vector_type(8)));
typedef float f32x4 __attribute__((ext_vector_type(4)));
typedef int i32x4 __attribute__((ext_vector_type(4)));

#define MFMA16(A, B, C) __builtin_amdgcn_mfma_f32_16x16x32_f16(A, B, C, 0, 0, 0)

static constexpr int BSZ = 65536;
static constexpr int IN = 512;
static constexpr int H = 1024;

// W2[k][j] fp32 -> w2d[plane][j][k] f16 Dekker limbs: plane0 = f16(w),
// plane1 = f16((w - hi) * 2^11).
__global__ void prep_dekker(const float* __restrict__ src, f16* __restrict__ dst) {
    int idx = blockIdx.x * 256 + threadIdx.x;
    int k = idx >> 10;
    int j = idx & 1023;
    float w = src[(size_t)k * 1024 + j];
    f16 hi = (f16)w;
    float lo = (w - (float)hi) * 2048.0f;
    size_t o = (size_t)j * 1024 + k;
    dst[o] = hi;
    dst[o + (size_t)H * H] = (f16)lo;
}

// k1: fp32 k-ordered FMA-chain GEMM (BLAS-replica) + fp32-replica LIF -> spike masks.
// tile 64 b-rows x 256 h-cols, 256 threads = 16 ht x 16 bt, thread = 4b x 16h.
__global__ __launch_bounds__(256, 2) void k1_chain(
    const float* __restrict__ x, const float* __restrict__ w1,
    const float* __restrict__ b1, unsigned short* __restrict__ s1b) {
    __shared__ float xs[32][65];    // [k][b] (+1 pad)
    __shared__ float ws[32][256];   // [k][h]
    const int hblk = blockIdx.x;    // 4
    const int bblk = blockIdx.y;    // 1024
    const int tid = threadIdx.x;
    const int ht = tid & 15, bt = tid >> 4;
    const int h0 = hblk * 256, b0 = bblk * 64;

    float acc[4][16] = {};

    for (int kc = 0; kc < 512; kc += 32) {
        float4 xv[2], wv[8];
#pragma unroll
        for (int i = 0; i < 2; ++i) {
            int idx = tid + 256 * i;            // 512 f4: 64 rows x 8 segs
            int br = idx >> 3, ks = idx & 7;
            xv[i] = *(const float4*)&x[(size_t)(b0 + br) * IN + kc + ks * 4];
        }
#pragma unroll
        for (int i = 0; i < 8; ++i) {
            int idx = tid + 256 * i;            // 2048 f4: 32 rows x 64 segs
            int kr = idx >> 6, c4 = idx & 63;
            wv[i] = *(const float4*)&w1[(size_t)(kc + kr) * H + h0 + c4 * 4];
        }
        __syncthreads();
#pragma unroll
        for (int i = 0; i < 2; ++i) {
            int idx = tid + 256 * i;
            int br = idx >> 3, ks = idx & 7;
            xs[ks * 4 + 0][br] = xv[i].x;
            xs[ks * 4 + 1][br] = xv[i].y;
            xs[ks * 4 + 2][br] = xv[i].z;
            xs[ks * 4 + 3][br] = xv[i].w;
        }
#pragma unroll
        for (int i = 0; i < 8; ++i) {
            int idx = tid + 256 * i;
            int kr = idx >> 6, c4 = idx & 63;
            *(float4*)&ws[kr][c4 * 4] = wv[i];
        }
        __syncthreads();
#pragma unroll
        for (int k = 0; k < 32; ++k) {
            float xr[4];
#pragma unroll
            for (int i = 0; i < 4; ++i) xr[i] = xs[k][bt * 4 + i];
            float wr[16];
#pragma unroll
            for (int g = 0; g < 4; ++g) {
                float4 t = *(const float4*)&ws[k][ht * 16 + g * 4];
                wr[g * 4 + 0] = t.x; wr[g * 4 + 1] = t.y;
                wr[g * 4 + 2] = t.z; wr[g * 4 + 3] = t.w;
            }
#pragma unroll
            for (int i = 0; i < 4; ++i)
#pragma unroll
                for (int j = 0; j < 16; ++j)
                    acc[i][j] = fmaf(xr[i], wr[j], acc[i][j]);  // strict k-order chain
        }
    }

    float b1v[16];
#pragma unroll
    for (int j = 0; j < 16; ++j) b1v[j] = b1[h0 + ht * 16 + j];
#pragma unroll
    for (int i = 0; i < 4; ++i) {
        unsigned short outb[16];
#pragma unroll
        for (int j = 0; j < 16; ++j) {
            float c = __fadd_rn(acc[i][j], b1v[j]);
            float m = 0.0f;
            unsigned bits = 0u;
#pragma unroll
            for (int t = 0; t < 10; ++t) {
                float rst = (m > 1.0f) ? 1.0f : 0.0f;
                m = __fmul_rn(0.9f, m);
                m = __fadd_rn(m, c);
                m = __fsub_rn(m, rst);
                if (m > 1.0f) bits |= (1u << t);
            }
            outb[j] = (unsigned short)bits;
        }
        size_t off = (size_t)(b0 + bt * 4 + i) * H + h0 + ht * 16;
        *(int4*)&s1b[off] = ((const int4*)outb)[0];
        *(int4*)&s1b[off + 8] = ((const int4*)outb)[1];
    }
}

// k2: spike GEMM. Block = 64 rows x 32 cols, 512 threads = 8 waves:
// wave = (strip = w&3 -> rows strip*16..+16) x (thalf = w>>2 -> t 0-4 or 5-9).
__global__ __launch_bounds__(512, 4) void k2_spikes_gemm(
    const unsigned short* __restrict__ s1bits, const f16* __restrict__ w2d,
    const float* __restrict__ b2, const float* __restrict__ wo,
    float* __restrict__ po) {
    __shared__ unsigned short As[2][64][40];   // [buf][row][k] stride 40 (80B rows)
    __shared__ f16 Bs[2][2][32][40];           // [buf][plane][j][k]
    __shared__ float m2x[4][64][8];            // m2 handoff t4 -> t5
    const int jblk = blockIdx.x, bblk = blockIdx.y;
    const int tid = threadIdx.x;
    const int lane = tid & 63, wave = tid >> 6;
    const int strip = wave & 3, thalf = wave >> 2;
    const int l15 = lane & 15, loct = lane >> 4;
    const int t0 = thalf * 5;

    // staging role: threads 0-255 stage A (64 rows x 4 segs), 256-511 stage B
    const bool stageB = (tid >= 256);
    const int s = tid & 255;
    const int arow = s >> 2, aseg = s & 3;
    const int bpl = s >> 7, brow = (s >> 2) & 31, bseg = s & 3;

    const unsigned short* ag = s1bits + (size_t)(bblk * 64 + arow) * 1024 + aseg * 8;
    const f16* bg = w2d + (size_t)bpl * H * H + (size_t)(jblk * 32 + brow) * 1024 + bseg * 8;

    f32x4 acc[5][2][2] = {};   // [tt][plane][colfrag] = 80 VGPRs

    i32x4 gv = stageB ? *(const i32x4*)bg : *(const i32x4*)ag;

    int buf = 0;
    for (int kc = 0; kc < 1024; kc += 32) {
        if (stageB) *(i32x4*)&Bs[buf][bpl][brow][bseg * 8] = gv;
        else        *(i32x4*)&As[buf][arow][aseg * 8] = gv;
        int kn = (kc + 32) & 1023;   // wraps to 0 on last iter (dummy prefetch)
        i32x4 gn = stageB ? *(const i32x4*)(bg + kn) : *(const i32x4*)(ag + kn);
        __syncthreads();
        i32x4 am = *(const i32x4*)&As[buf][strip * 16 + l15][loct * 8];
        f16x8 bf[2][2];
#pragma unroll
        for (int p = 0; p < 2; ++p)
#pragma unroll
            for (int cf = 0; cf < 2; ++cf)
                bf[p][cf] = *(const f16x8*)&Bs[buf][p][cf * 16 + l15][loct * 8];
#pragma unroll
        for (int tt = 0; tt < 5; ++tt) {
            const int sh = 10 - (t0 + tt);
            union { i32x4 i; f16x8 h; } u;
#pragma unroll
            for (int q = 0; q < 4; ++q)
                u.i[q] = (int)(((unsigned)am[q] << sh) & 0x04000400u);
            acc[tt][0][0] = MFMA16(u.h, bf[0][0], acc[tt][0][0]);
            acc[tt][0][1] = MFMA16(u.h, bf[0][1], acc[tt][0][1]);
            acc[tt][1][0] = MFMA16(u.h, bf[1][0], acc[tt][1][0]);
            acc[tt][1][1] = MFMA16(u.h, bf[1][1], acc[tt][1][1]);
        }
        gv = gn;
        buf ^= 1;
    }

    // epilogue: Dekker combine (unpack scale folded in: 16384, 8),
    // fp32-replica LIF-2 split across t-halves with LDS m2 handoff.
    int col0 = jblk * 32 + l15;
    float b2v0 = b2[col0], b2v1 = b2[col0 + 16];
    double wov0 = (double)wo[col0], wov1 = (double)wo[col0 + 16];
    int rowb = bblk * 64 + strip * 16 + loct * 4;
    float m2a[4] = {0.0f, 0.0f, 0.0f, 0.0f};
    float m2b[4] = {0.0f, 0.0f, 0.0f, 0.0f};

    if (thalf == 0) {
#pragma unroll
        for (int tt = 0; tt < 5; ++tt) {
#pragma unroll
            for (int r = 0; r < 4; ++r) {
                float i0 = (float)((double)acc[tt][0][0][r] * 16384.0 + (double)acc[tt][1][0][r] * 8.0);
                i0 = __fadd_rn(i0, b2v0);
                float rst0 = (m2a[r] > 1.0f) ? 1.0f : 0.0f;
                m2a[r] = __fmul_rn(0.9f, m2a[r]);
                m2a[r] = __fadd_rn(m2a[r], i0);
                m2a[r] = __fsub_rn(m2a[r], rst0);
                float i1 = (float)((double)acc[tt][0][1][r] * 16384.0 + (double)acc[tt][1][1][r] * 8.0);
                i1 = __fadd_rn(i1, b2v1);
                float rst1 = (m2b[r] > 1.0f) ? 1.0f : 0.0f;
                m2b[r] = __fmul_rn(0.9f, m2b[r]);
                m2b[r] = __fadd_rn(m2b[r], i1);
                m2b[r] = __fsub_rn(m2b[r], rst1);
                double pv = ((m2a[r] > 1.0f) ? wov0 : 0.0) + ((m2b[r] > 1.0f) ? wov1 : 0.0);
                pv += __shfl_xor(pv, 1);
                pv += __shfl_xor(pv, 2);
                pv += __shfl_xor(pv, 4);
                pv += __shfl_xor(pv, 8);
                if (l15 == r)
                    po[(size_t)(tt * 32 + jblk) * BSZ + rowb + r] = (float)pv;
            }
        }
#pragma unroll
        for (int r = 0; r < 4; ++r) {
            m2x[strip][lane][r] = m2a[r];
            m2x[strip][lane][4 + r] = m2b[r];
        }
    }
    __syncthreads();
    if (thalf == 1) {
#pragma unroll
        for (int r = 0; r < 4; ++r) {
            m2a[r] = m2x[strip][lane][r];
            m2b[r] = m2x[strip][lane][4 + r];
        }
#pragma unroll
        for (int tt = 0; tt < 5; ++tt) {
#pragma unroll
            for (int r = 0; r < 4; ++r) {
                float i0 = (float)((double)acc[tt][0][0][r] * 16384.0 + (double)acc[tt][1][0][r] * 8.0);
                i0 = __fadd_rn(i0, b2v0);
                float rst0 = (m2a[r] > 1.0f) ? 1.0f : 0.0f;
                m2a[r] = __fmul_rn(0.9f, m2a[r]);
                m2a[r] = __fadd_rn(m2a[r], i0);
                m2a[r] = __fsub_rn(m2a[r], rst0);
                float i1 = (float)((double)acc[tt][0][1][r] * 16384.0 + (double)acc[tt][1][1][r] * 8.0);
                i1 = __fadd_rn(i1, b2v1);
                float rst1 = (m2b[r] > 1.0f) ? 1.0f : 0.0f;
                m2b[r] = __fmul_rn(0.9f, m2b[r]);
                m2b[r] = __fadd_rn(m2b[r], i1);
                m2b[r] = __fsub_rn(m2b[r], rst1);
                double pv = ((m2a[r] > 1.0f) ? wov0 : 0.0) + ((m2b[r] > 1.0f) ? wov1 : 0.0);
                pv += __shfl_xor(pv, 1);
                pv += __shfl_xor(pv, 2);
                pv += __shfl_xor(pv, 4);
                pv += __shfl_xor(pv, 8);
                if (l15 == r)
                    po[(size_t)((5 + tt) * 32 + jblk) * BSZ + rowb + r] = (float)pv;
            }
        }
    }
}

// k3: sum 32 partials (ascending j-blocks), fp32-replica LIF-out, mean.
__global__ void k3_out(const float* __restrict__ po, const float* __restrict__ bo,
                       float* __restrict__ out) {
    int b = blockIdx.x * 256 + threadIdx.x;
    float mo = 0.0f, s = 0.0f;
    float bov = bo[0];
    for (int t = 0; t < 10; ++t) {
        float inp = 0.0f;
#pragma unroll
        for (int jb = 0; jb < 32; ++jb) inp += po[(size_t)(t * 32 + jb) * BSZ + b];
        inp = __fadd_rn(inp, bov);
        float rst = (mo > 1.0f) ? 1.0f : 0.0f;
        mo = __fmul_rn(0.9f, mo);
        mo = __fadd_rn(mo, inp);
        mo = __fsub_rn(mo, rst);
        s += mo;
    }
    out[b] = s / 10.0f;
}

extern "C" void kernel_launch(void* const* d_in, const int* in_sizes, int n_in,
                              void* d_out, int out_size, void* d_ws, size_t ws_size,
                              hipStream_t stream) {
    (void)in_sizes; (void)n_in; (void)out_size; (void)ws_size;
    const float* x  = (const float*)d_in[0];
    const float* W1 = (const float*)d_in[1];
    const float* b1 = (const float*)d_in[2];
    const float* W2 = (const float*)d_in[3];
    const float* b2 = (const float*)d_in[4];
    const float* Wo = (const float*)d_in[5];
    const float* bo = (const float*)d_in[6];
    float* out = (float*)d_out;

    char* ws = (char*)d_ws;
    f16* w2d = (f16*)ws;                                                   // 4 MiB @ 0
    unsigned short* s1bits = (unsigned short*)(ws + ((size_t)16 << 20));   // 128 MiB
    float* po = (float*)(ws + ((size_t)160 << 20));                        // 80 MiB

    prep_dekker<<<dim3((H * H) / 256), 256, 0, stream>>>(W2, w2d);
    k1_chain<<<dim3(4, BSZ / 64), 256, 0, stream>>>(x, W1, b1, s1bits);
    k2_spikes_gemm<<<dim3(H / 32, BSZ / 64), 512, 0, stream>>>(s1bits, w2d, b2, Wo, po);
    k3_out<<<dim3(BSZ / 256), 256, 0, stream>>>(po, bo, out);
}

// Round 8
// 3553.770 us; speedup vs baseline: 1.2319x; 1.0193x over previous
//
#include <hip/hip_runtime.h>
#include <cstdint>
#include <cstddef>

// SNN pipeline, np-fp32-replication strategy (round 8):
//  k1: cur1 = x@W1+b1 as fp32 k-ascending FMA chains (OpenBLAS replica) + fp32-replica
//      LIF-1 -> packed 10-bit spike masks (unchanged, passing).
//  k2: spike GEMM, 2-plane Dekker f16 split of W2. 512-thread blocks, 8 waves =
//      4 row-strips x 2 t-halves; acc[5][2][2] = 80 VGPRs/wave, 4 waves/SIMD.
//      LDS layout UNPADDED (32-elem rows, 64 B): every ds_write_b128/ds_read_b128
//      covers 16 consecutive rows = contiguous 1024 B per wave = ZERO bank conflicts
//      (round-7's stride-40 pad was generating 2.38e8 conflict cycles).
//      Double-buffered, 1 barrier/iter, register prefetch. Unpack 2 VALU/dword:
//      (mask << (10-t)) & 0x04000400 -> exact f16 {0,2^-14}, scale folded into
//      fp64 epilogue combine. LIF-2 m2 handoff t4->t5 via LDS.
//  k3: sum 32 partials, fp32-replica LIF-out, mean -> d_out.
// ws: w2d 4MiB @0 | s1bits 128MiB @16MiB | po 80MiB @160MiB

typedef _Float16 f16;
typedef _Float16 f16x8 __attribute__((ext_vector_type(8)));
typedef float f32x4 __attribute__((ext_vector_type(4)));
typedef int i32x4 __attribute__((ext_vector_type(4)));

#define MFMA16(A, B, C) __builtin_amdgcn_mfma_f32_16x16x32_f16(A, B, C, 0, 0, 0)

static constexpr int BSZ = 65536;
static constexpr int IN = 512;
static constexpr int H = 1024;

// W2[k][j] fp32 -> w2d[plane][j][k] f16 Dekker limbs: plane0 = f16(w),
// plane1 = f16((w - hi) * 2^11).
__global__ void prep_dekker(const float* __restrict__ src, f16* __restrict__ dst) {
    int idx = blockIdx.x * 256 + threadIdx.x;
    int k = idx >> 10;
    int j = idx & 1023;
    float w = src[(size_t)k * 1024 + j];
    f16 hi = (f16)w;
    float lo = (w - (float)hi) * 2048.0f;
    size_t o = (size_t)j * 1024 + k;
    dst[o] = hi;
    dst[o + (size_t)H * H] = (f16)lo;
}

// k1: fp32 k-ordered FMA-chain GEMM (BLAS-replica) + fp32-replica LIF -> spike masks.
// tile 64 b-rows x 256 h-cols, 256 threads = 16 ht x 16 bt, thread = 4b x 16h.
__global__ __launch_bounds__(256, 2) void k1_chain(
    const float* __restrict__ x, const float* __restrict__ w1,
    const float* __restrict__ b1, unsigned short* __restrict__ s1b) {
    __shared__ float xs[32][65];    // [k][b] (+1 pad)
    __shared__ float ws[32][256];   // [k][h]
    const int hblk = blockIdx.x;    // 4
    const int bblk = blockIdx.y;    // 1024
    const int tid = threadIdx.x;
    const int ht = tid & 15, bt = tid >> 4;
    const int h0 = hblk * 256, b0 = bblk * 64;

    float acc[4][16] = {};

    for (int kc = 0; kc < 512; kc += 32) {
        float4 xv[2], wv[8];
#pragma unroll
        for (int i = 0; i < 2; ++i) {
            int idx = tid + 256 * i;            // 512 f4: 64 rows x 8 segs
            int br = idx >> 3, ks = idx & 7;
            xv[i] = *(const float4*)&x[(size_t)(b0 + br) * IN + kc + ks * 4];
        }
#pragma unroll
        for (int i = 0; i < 8; ++i) {
            int idx = tid + 256 * i;            // 2048 f4: 32 rows x 64 segs
            int kr = idx >> 6, c4 = idx & 63;
            wv[i] = *(const float4*)&w1[(size_t)(kc + kr) * H + h0 + c4 * 4];
        }
        __syncthreads();
#pragma unroll
        for (int i = 0; i < 2; ++i) {
            int idx = tid + 256 * i;
            int br = idx >> 3, ks = idx & 7;
            xs[ks * 4 + 0][br] = xv[i].x;
            xs[ks * 4 + 1][br] = xv[i].y;
            xs[ks * 4 + 2][br] = xv[i].z;
            xs[ks * 4 + 3][br] = xv[i].w;
        }
#pragma unroll
        for (int i = 0; i < 8; ++i) {
            int idx = tid + 256 * i;
            int kr = idx >> 6, c4 = idx & 63;
            *(float4*)&ws[kr][c4 * 4] = wv[i];
        }
        __syncthreads();
#pragma unroll
        for (int k = 0; k < 32; ++k) {
            float xr[4];
#pragma unroll
            for (int i = 0; i < 4; ++i) xr[i] = xs[k][bt * 4 + i];
            float wr[16];
#pragma unroll
            for (int g = 0; g < 4; ++g) {
                float4 t = *(const float4*)&ws[k][ht * 16 + g * 4];
                wr[g * 4 + 0] = t.x; wr[g * 4 + 1] = t.y;
                wr[g * 4 + 2] = t.z; wr[g * 4 + 3] = t.w;
            }
#pragma unroll
            for (int i = 0; i < 4; ++i)
#pragma unroll
                for (int j = 0; j < 16; ++j)
                    acc[i][j] = fmaf(xr[i], wr[j], acc[i][j]);  // strict k-order chain
        }
    }

    float b1v[16];
#pragma unroll
    for (int j = 0; j < 16; ++j) b1v[j] = b1[h0 + ht * 16 + j];
#pragma unroll
    for (int i = 0; i < 4; ++i) {
        unsigned short outb[16];
#pragma unroll
        for (int j = 0; j < 16; ++j) {
            float c = __fadd_rn(acc[i][j], b1v[j]);
            float m = 0.0f;
            unsigned bits = 0u;
#pragma unroll
            for (int t = 0; t < 10; ++t) {
                float rst = (m > 1.0f) ? 1.0f : 0.0f;
                m = __fmul_rn(0.9f, m);
                m = __fadd_rn(m, c);
                m = __fsub_rn(m, rst);
                if (m > 1.0f) bits |= (1u << t);
            }
            outb[j] = (unsigned short)bits;
        }
        size_t off = (size_t)(b0 + bt * 4 + i) * H + h0 + ht * 16;
        *(int4*)&s1b[off] = ((const int4*)outb)[0];
        *(int4*)&s1b[off + 8] = ((const int4*)outb)[1];
    }
}

// k2: spike GEMM. Block = 64 rows x 32 cols, 512 threads = 8 waves:
// wave = (strip = w&3 -> rows strip*16..+16) x (thalf = w>>2 -> t 0-4 or 5-9).
__global__ __launch_bounds__(512, 4) void k2_spikes_gemm(
    const unsigned short* __restrict__ s1bits, const f16* __restrict__ w2d,
    const float* __restrict__ b2, const float* __restrict__ wo,
    float* __restrict__ po) {
    __shared__ unsigned short As[2][64][32];   // [buf][row][k] UNPADDED 64 B rows
    __shared__ f16 Bs[2][2][32][32];           // [buf][plane][j][k] UNPADDED
    __shared__ float m2x[4][64][8];            // m2 handoff t4 -> t5
    const int jblk = blockIdx.x, bblk = blockIdx.y;
    const int tid = threadIdx.x;
    const int lane = tid & 63, wave = tid >> 6;
    const int strip = wave & 3, thalf = wave >> 2;
    const int l15 = lane & 15, loct = lane >> 4;
    const int t0 = thalf * 5;

    // staging role: threads 0-255 stage A (64 rows x 4 segs), 256-511 stage B
    const bool stageB = (tid >= 256);
    const int s = tid & 255;
    const int arow = s >> 2, aseg = s & 3;
    const int bpl = s >> 7, brow = (s >> 2) & 31, bseg = s & 3;

    const unsigned short* ag = s1bits + (size_t)(bblk * 64 + arow) * 1024 + aseg * 8;
    const f16* bg = w2d + (size_t)bpl * H * H + (size_t)(jblk * 32 + brow) * 1024 + bseg * 8;

    f32x4 acc[5][2][2] = {};   // [tt][plane][colfrag] = 80 VGPRs

    i32x4 gv = stageB ? *(const i32x4*)bg : *(const i32x4*)ag;

    int buf = 0;
    for (int kc = 0; kc < 1024; kc += 32) {
        if (stageB) *(i32x4*)&Bs[buf][bpl][brow][bseg * 8] = gv;
        else        *(i32x4*)&As[buf][arow][aseg * 8] = gv;
        int kn = (kc + 32) & 1023;   // wraps to 0 on last iter (dummy prefetch)
        i32x4 gn = stageB ? *(const i32x4*)(bg + kn) : *(const i32x4*)(ag + kn);
        __syncthreads();
        i32x4 am = *(const i32x4*)&As[buf][strip * 16 + l15][loct * 8];
        f16x8 bf[2][2];
#pragma unroll
        for (int p = 0; p < 2; ++p)
#pragma unroll
            for (int cf = 0; cf < 2; ++cf)
                bf[p][cf] = *(const f16x8*)&Bs[buf][p][cf * 16 + l15][loct * 8];
#pragma unroll
        for (int tt = 0; tt < 5; ++tt) {
            const int sh = 10 - (t0 + tt);
            union { i32x4 i; f16x8 h; } u;
#pragma unroll
            for (int q = 0; q < 4; ++q)
                u.i[q] = (int)(((unsigned)am[q] << sh) & 0x04000400u);
            acc[tt][0][0] = MFMA16(u.h, bf[0][0], acc[tt][0][0]);
            acc[tt][0][1] = MFMA16(u.h, bf[0][1], acc[tt][0][1]);
            acc[tt][1][0] = MFMA16(u.h, bf[1][0], acc[tt][1][0]);
            acc[tt][1][1] = MFMA16(u.h, bf[1][1], acc[tt][1][1]);
        }
        gv = gn;
        buf ^= 1;
    }

    // epilogue: Dekker combine (unpack scale folded in: 16384, 8),
    // fp32-replica LIF-2 split across t-halves with LDS m2 handoff.
    int col0 = jblk * 32 + l15;
    float b2v0 = b2[col0], b2v1 = b2[col0 + 16];
    double wov0 = (double)wo[col0], wov1 = (double)wo[col0 + 16];
    int rowb = bblk * 64 + strip * 16 + loct * 4;
    float m2a[4] = {0.0f, 0.0f, 0.0f, 0.0f};
    float m2b[4] = {0.0f, 0.0f, 0.0f, 0.0f};

    if (thalf == 0) {
#pragma unroll
        for (int tt = 0; tt < 5; ++tt) {
#pragma unroll
            for (int r = 0; r < 4; ++r) {
                float i0 = (float)((double)acc[tt][0][0][r] * 16384.0 + (double)acc[tt][1][0][r] * 8.0);
                i0 = __fadd_rn(i0, b2v0);
                float rst0 = (m2a[r] > 1.0f) ? 1.0f : 0.0f;
                m2a[r] = __fmul_rn(0.9f, m2a[r]);
                m2a[r] = __fadd_rn(m2a[r], i0);
                m2a[r] = __fsub_rn(m2a[r], rst0);
                float i1 = (float)((double)acc[tt][0][1][r] * 16384.0 + (double)acc[tt][1][1][r] * 8.0);
                i1 = __fadd_rn(i1, b2v1);
                float rst1 = (m2b[r] > 1.0f) ? 1.0f : 0.0f;
                m2b[r] = __fmul_rn(0.9f, m2b[r]);
                m2b[r] = __fadd_rn(m2b[r], i1);
                m2b[r] = __fsub_rn(m2b[r], rst1);
                double pv = ((m2a[r] > 1.0f) ? wov0 : 0.0) + ((m2b[r] > 1.0f) ? wov1 : 0.0);
                pv += __shfl_xor(pv, 1);
                pv += __shfl_xor(pv, 2);
                pv += __shfl_xor(pv, 4);
                pv += __shfl_xor(pv, 8);
                if (l15 == r)
                    po[(size_t)(tt * 32 + jblk) * BSZ + rowb + r] = (float)pv;
            }
        }
#pragma unroll
        for (int r = 0; r < 4; ++r) {
            m2x[strip][lane][r] = m2a[r];
            m2x[strip][lane][4 + r] = m2b[r];
        }
    }
    __syncthreads();
    if (thalf == 1) {
#pragma unroll
        for (int r = 0; r < 4; ++r) {
            m2a[r] = m2x[strip][lane][r];
            m2b[r] = m2x[strip][lane][4 + r];
        }
#pragma unroll
        for (int tt = 0; tt < 5; ++tt) {
#pragma unroll
            for (int r = 0; r < 4; ++r) {
                float i0 = (float)((double)acc[tt][0][0][r] * 16384.0 + (double)acc[tt][1][0][r] * 8.0);
                i0 = __fadd_rn(i0, b2v0);
                float rst0 = (m2a[r] > 1.0f) ? 1.0f : 0.0f;
                m2a[r] = __fmul_rn(0.9f, m2a[r]);
                m2a[r] = __fadd_rn(m2a[r], i0);
                m2a[r] = __fsub_rn(m2a[r], rst0);
                float i1 = (float)((double)acc[tt][0][1][r] * 16384.0 + (double)acc[tt][1][1][r] * 8.0);
                i1 = __fadd_rn(i1, b2v1);
                float rst1 = (m2b[r] > 1.0f) ? 1.0f : 0.0f;
                m2b[r] = __fmul_rn(0.9f, m2b[r]);
                m2b[r] = __fadd_rn(m2b[r], i1);
                m2b[r] = __fsub_rn(m2b[r], rst1);
                double pv = ((m2a[r] > 1.0f) ? wov0 : 0.0) + ((m2b[r] > 1.0f) ? wov1 : 0.0);
                pv += __shfl_xor(pv, 1);
                pv += __shfl_xor(pv, 2);
                pv += __shfl_xor(pv, 4);
                pv += __shfl_xor(pv, 8);
                if (l15 == r)
                    po[(size_t)((5 + tt) * 32 + jblk) * BSZ + rowb + r] = (float)pv;
            }
        }
    }
}

// k3: sum 32 partials (ascending j-blocks), fp32-replica LIF-out, mean.
__global__ void k3_out(const float* __restrict__ po, const float* __restrict__ bo,
                       float* __restrict__ out) {
    int b = blockIdx.x * 256 + threadIdx.x;
    float mo = 0.0f, s = 0.0f;
    float bov = bo[0];
    for (int t = 0; t < 10; ++t) {
        float inp = 0.0f;
#pragma unroll
        for (int jb = 0; jb < 32; ++jb) inp += po[(size_t)(t * 32 + jb) * BSZ + b];
        inp = __fadd_rn(inp, bov);
        float rst = (mo > 1.0f) ? 1.0f : 0.0f;
        mo = __fmul_rn(0.9f, mo);
        mo = __fadd_rn(mo, inp);
        mo = __fsub_rn(mo, rst);
        s += mo;
    }
    out[b] = s / 10.0f;
}

extern "C" void kernel_launch(void* const* d_in, const int* in_sizes, int n_in,
                              void* d_out, int out_size, void* d_ws, size_t ws_size,
                              hipStream_t stream) {
    (void)in_sizes; (void)n_in; (void)out_size; (void)ws_size;
    const float* x  = (const float*)d_in[0];
    const float* W1 = (const float*)d_in[1];
    const float* b1 = (const float*)d_in[2];
    const float* W2 = (const float*)d_in[3];
    const float* b2 = (const float*)d_in[4];
    const float* Wo = (const float*)d_in[5];
    const float* bo = (const float*)d_in[6];
    float* out = (float*)d_out;

    char* ws = (char*)d_ws;
    f16* w2d = (f16*)ws;                                                   // 4 MiB @ 0
    unsigned short* s1bits = (unsigned short*)(ws + ((size_t)16 << 20));   // 128 MiB
    float* po = (float*)(ws + ((size_t)160 << 20));                        // 80 MiB

    prep_dekker<<<dim3((H * H) / 256), 256, 0, stream>>>(W2, w2d);
    k1_chain<<<dim3(4, BSZ / 64), 256, 0, stream>>>(x, W1, b1, s1bits);
    k2_spikes_gemm<<<dim3(H / 32, BSZ / 64), 512, 0, stream>>>(s1bits, w2d, b2, Wo, po);
    k3_out<<<dim3(BSZ / 256), 256, 0, stream>>>(po, bo, out);
}

// Round 9
// 3388.322 us; speedup vs baseline: 1.2921x; 1.0488x over previous
//
#include <hip/hip_runtime.h>
#include <cstdint>
#include <cstddef>

// SNN pipeline, np-fp32-replication strategy (round 9):
//  k1: cur1 = x@W1+b1 as fp32 k-ascending FMA chains (OpenBLAS replica) + fp32-replica
//      LIF-1 -> packed 10-bit spike masks (unchanged, passing).
//  k2: spike GEMM, 2-plane Dekker f16 split of W2. 512 threads = 4 row-strips x 2
//      t-halves, acc[5][2][2]. LDS tiles stored in MFMA-FRAGMENT-LINEAR order:
//      slot = (seg<<4)|row, 16 B per lane -> ds_read_b128 AND ds_write_b128 are
//      both perfectly lane-stride-1 = ZERO bank conflicts (round-8's row-major
//      64 B rows gave an 8-banks/8-lanes map = 8-way conflict on every read).
//      BK=64: 16 K-iters, half the barrier drains. 64-bit unpack:
//      (mask64 << (10-t)) & 0x0400040004000400 -> exact f16 {0,2^-14} x4, safe
//      (shift<=10, kept bits 10/26). Scales folded into fp64 epilogue combine.
//      fp32-replica LIF-2, LDS m2 handoff t4->t5, shfl Wo partials.
//  k3: sum 32 partials, fp32-replica LIF-out, mean -> d_out.
// ws: w2d 4MiB @0 | s1bits 128MiB @16MiB | po 80MiB @160MiB

typedef _Float16 f16;
typedef _Float16 f16x8 __attribute__((ext_vector_type(8)));
typedef float f32x4 __attribute__((ext_vector_type(4)));
typedef int i32x4 __attribute__((ext_vector_type(4)));

#define MFMA16(A, B, C) __builtin_amdgcn_mfma_f32_16x16x32_f16(A, B, C, 0, 0, 0)

static constexpr int BSZ = 65536;
static constexpr int IN = 512;
static constexpr int H = 1024;

// W2[k][j] fp32 -> w2d[plane][j][k] f16 Dekker limbs: plane0 = f16(w),
// plane1 = f16((w - hi) * 2^11).
__global__ void prep_dekker(const float* __restrict__ src, f16* __restrict__ dst) {
    int idx = blockIdx.x * 256 + threadIdx.x;
    int k = idx >> 10;
    int j = idx & 1023;
    float w = src[(size_t)k * 1024 + j];
    f16 hi = (f16)w;
    float lo = (w - (float)hi) * 2048.0f;
    size_t o = (size_t)j * 1024 + k;
    dst[o] = hi;
    dst[o + (size_t)H * H] = (f16)lo;
}

// k1: fp32 k-ordered FMA-chain GEMM (BLAS-replica) + fp32-replica LIF -> spike masks.
// tile 64 b-rows x 256 h-cols, 256 threads = 16 ht x 16 bt, thread = 4b x 16h.
__global__ __launch_bounds__(256, 2) void k1_chain(
    const float* __restrict__ x, const float* __restrict__ w1,
    const float* __restrict__ b1, unsigned short* __restrict__ s1b) {
    __shared__ float xs[32][65];    // [k][b] (+1 pad)
    __shared__ float ws[32][256];   // [k][h]
    const int hblk = blockIdx.x;    // 4
    const int bblk = blockIdx.y;    // 1024
    const int tid = threadIdx.x;
    const int ht = tid & 15, bt = tid >> 4;
    const int h0 = hblk * 256, b0 = bblk * 64;

    float acc[4][16] = {};

    for (int kc = 0; kc < 512; kc += 32) {
        float4 xv[2], wv[8];
#pragma unroll
        for (int i = 0; i < 2; ++i) {
            int idx = tid + 256 * i;            // 512 f4: 64 rows x 8 segs
            int br = idx >> 3, ks = idx & 7;
            xv[i] = *(const float4*)&x[(size_t)(b0 + br) * IN + kc + ks * 4];
        }
#pragma unroll
        for (int i = 0; i < 8; ++i) {
            int idx = tid + 256 * i;            // 2048 f4: 32 rows x 64 segs
            int kr = idx >> 6, c4 = idx & 63;
            wv[i] = *(const float4*)&w1[(size_t)(kc + kr) * H + h0 + c4 * 4];
        }
        __syncthreads();
#pragma unroll
        for (int i = 0; i < 2; ++i) {
            int idx = tid + 256 * i;
            int br = idx >> 3, ks = idx & 7;
            xs[ks * 4 + 0][br] = xv[i].x;
            xs[ks * 4 + 1][br] = xv[i].y;
            xs[ks * 4 + 2][br] = xv[i].z;
            xs[ks * 4 + 3][br] = xv[i].w;
        }
#pragma unroll
        for (int i = 0; i < 8; ++i) {
            int idx = tid + 256 * i;
            int kr = idx >> 6, c4 = idx & 63;
            *(float4*)&ws[kr][c4 * 4] = wv[i];
        }
        __syncthreads();
#pragma unroll
        for (int k = 0; k < 32; ++k) {
            float xr[4];
#pragma unroll
            for (int i = 0; i < 4; ++i) xr[i] = xs[k][bt * 4 + i];
            float wr[16];
#pragma unroll
            for (int g = 0; g < 4; ++g) {
                float4 t = *(const float4*)&ws[k][ht * 16 + g * 4];
                wr[g * 4 + 0] = t.x; wr[g * 4 + 1] = t.y;
                wr[g * 4 + 2] = t.z; wr[g * 4 + 3] = t.w;
            }
#pragma unroll
            for (int i = 0; i < 4; ++i)
#pragma unroll
                for (int j = 0; j < 16; ++j)
                    acc[i][j] = fmaf(xr[i], wr[j], acc[i][j]);  // strict k-order chain
        }
    }

    float b1v[16];
#pragma unroll
    for (int j = 0; j < 16; ++j) b1v[j] = b1[h0 + ht * 16 + j];
#pragma unroll
    for (int i = 0; i < 4; ++i) {
        unsigned short outb[16];
#pragma unroll
        for (int j = 0; j < 16; ++j) {
            float c = __fadd_rn(acc[i][j], b1v[j]);
            float m = 0.0f;
            unsigned bits = 0u;
#pragma unroll
            for (int t = 0; t < 10; ++t) {
                float rst = (m > 1.0f) ? 1.0f : 0.0f;
                m = __fmul_rn(0.9f, m);
                m = __fadd_rn(m, c);
                m = __fsub_rn(m, rst);
                if (m > 1.0f) bits |= (1u << t);
            }
            outb[j] = (unsigned short)bits;
        }
        size_t off = (size_t)(b0 + bt * 4 + i) * H + h0 + ht * 16;
        *(int4*)&s1b[off] = ((const int4*)outb)[0];
        *(int4*)&s1b[off + 8] = ((const int4*)outb)[1];
    }
}

// k2: spike GEMM. Block = 64 rows x 32 cols, 512 threads = 8 waves:
// wave = (strip = w&3) x (thalf = w>>2). Fragment-linear LDS, BK=64.
__global__ __launch_bounds__(512, 4) void k2_spikes_gemm(
    const unsigned short* __restrict__ s1bits, const f16* __restrict__ w2d,
    const float* __restrict__ b2, const float* __restrict__ wo,
    float* __restrict__ po) {
    __shared__ i32x4 AL[2][2][4][64];       // [buf][kch][strip][lane-slot] 16 KB
    __shared__ i32x4 BL[2][2][2][2][64];    // [buf][kch][plane][cf][lane-slot] 16 KB
    __shared__ float m2x[4][64][8];         // m2 handoff t4 -> t5, 8 KB
    const int jblk = blockIdx.x, bblk = blockIdx.y;
    const int tid = threadIdx.x;
    const int lane = tid & 63, wave = tid >> 6;
    const int strip = wave & 3, thalf = wave >> 2;
    const int l15 = lane & 15, loct = lane >> 4;
    const int t0 = thalf * 5;

    // staging: threads 0-255 stage A, 256-511 stage B; slot = (seg<<4)|row
    // matches the MFMA fragment lane map -> stride-1 LDS writes AND reads.
    const bool stageB = (tid >= 256);
    const int s = tid & 255;
    const int sl15 = s & 15, sseg = (s >> 4) & 3;
    const int slot = (sseg << 4) | sl15;          // lane slot within its group
    const int astrip = s >> 6;                    // A: 4 strips
    const int bp = (s >> 7) & 1, bcf = (s >> 6) & 1;  // B: plane, colfrag

    const char* gsrc;
    if (stageB)
        gsrc = (const char*)(w2d + (size_t)bp * H * H
                             + (size_t)(jblk * 32 + bcf * 16 + sl15) * 1024 + sseg * 8);
    else
        gsrc = (const char*)(s1bits + (size_t)(bblk * 64 + astrip * 16 + sl15) * 1024 + sseg * 8);

    f32x4 acc[5][2][2] = {};   // [tt][plane][colfrag] = 80 regs

    i32x4 gv0 = *(const i32x4*)(gsrc);
    i32x4 gv1 = *(const i32x4*)(gsrc + 64);

    typedef union { i32x4 i; unsigned long long u[2]; f16x8 h; } U;

    int buf = 0;
    for (int kc = 0; kc < 1024; kc += 64) {
        if (stageB) {
            BL[buf][0][bp][bcf][slot] = gv0;
            BL[buf][1][bp][bcf][slot] = gv1;
        } else {
            AL[buf][0][astrip][slot] = gv0;
            AL[buf][1][astrip][slot] = gv1;
        }
        int kn = (kc + 64) & 1023;   // wraps to 0 on last iter (dummy prefetch)
        i32x4 gn0 = *(const i32x4*)(gsrc + kn * 2);
        i32x4 gn1 = *(const i32x4*)(gsrc + kn * 2 + 64);
        __syncthreads();
#pragma unroll
        for (int kch = 0; kch < 2; ++kch) {
            U m;
            m.i = AL[buf][kch][strip][lane];
            f16x8 bf[2][2];
#pragma unroll
            for (int p = 0; p < 2; ++p)
#pragma unroll
                for (int cf = 0; cf < 2; ++cf) {
                    U b; b.i = BL[buf][kch][p][cf][lane];
                    bf[p][cf] = b.h;
                }
#pragma unroll
            for (int tt = 0; tt < 5; ++tt) {
                const int sh = 10 - (t0 + tt);
                U r;
                r.u[0] = (m.u[0] << sh) & 0x0400040004000400ULL;
                r.u[1] = (m.u[1] << sh) & 0x0400040004000400ULL;
                acc[tt][0][0] = MFMA16(r.h, bf[0][0], acc[tt][0][0]);
                acc[tt][0][1] = MFMA16(r.h, bf[0][1], acc[tt][0][1]);
                acc[tt][1][0] = MFMA16(r.h, bf[1][0], acc[tt][1][0]);
                acc[tt][1][1] = MFMA16(r.h, bf[1][1], acc[tt][1][1]);
            }
        }
        gv0 = gn0; gv1 = gn1;
        buf ^= 1;
    }

    // epilogue: Dekker combine (unpack scale folded in: 16384, 8),
    // fp32-replica LIF-2 split across t-halves with LDS m2 handoff.
    int col0 = jblk * 32 + l15;
    float b2v0 = b2[col0], b2v1 = b2[col0 + 16];
    double wov0 = (double)wo[col0], wov1 = (double)wo[col0 + 16];
    int rowb = bblk * 64 + strip * 16 + loct * 4;
    float m2a[4] = {0.0f, 0.0f, 0.0f, 0.0f};
    float m2b[4] = {0.0f, 0.0f, 0.0f, 0.0f};

    if (thalf == 0) {
#pragma unroll
        for (int tt = 0; tt < 5; ++tt) {
#pragma unroll
            for (int r = 0; r < 4; ++r) {
                float i0 = (float)((double)acc[tt][0][0][r] * 16384.0 + (double)acc[tt][1][0][r] * 8.0);
                i0 = __fadd_rn(i0, b2v0);
                float rst0 = (m2a[r] > 1.0f) ? 1.0f : 0.0f;
                m2a[r] = __fmul_rn(0.9f, m2a[r]);
                m2a[r] = __fadd_rn(m2a[r], i0);
                m2a[r] = __fsub_rn(m2a[r], rst0);
                float i1 = (float)((double)acc[tt][0][1][r] * 16384.0 + (double)acc[tt][1][1][r] * 8.0);
                i1 = __fadd_rn(i1, b2v1);
                float rst1 = (m2b[r] > 1.0f) ? 1.0f : 0.0f;
                m2b[r] = __fmul_rn(0.9f, m2b[r]);
                m2b[r] = __fadd_rn(m2b[r], i1);
                m2b[r] = __fsub_rn(m2b[r], rst1);
                double pv = ((m2a[r] > 1.0f) ? wov0 : 0.0) + ((m2b[r] > 1.0f) ? wov1 : 0.0);
                pv += __shfl_xor(pv, 1);
                pv += __shfl_xor(pv, 2);
                pv += __shfl_xor(pv, 4);
                pv += __shfl_xor(pv, 8);
                if (l15 == r)
                    po[(size_t)(tt * 32 + jblk) * BSZ + rowb + r] = (float)pv;
            }
        }
#pragma unroll
        for (int r = 0; r < 4; ++r) {
            m2x[strip][lane][r] = m2a[r];
            m2x[strip][lane][4 + r] = m2b[r];
        }
    }
    __syncthreads();
    if (thalf == 1) {
#pragma unroll
        for (int r = 0; r < 4; ++r) {
            m2a[r] = m2x[strip][lane][r];
            m2b[r] = m2x[strip][lane][4 + r];
        }
#pragma unroll
        for (int tt = 0; tt < 5; ++tt) {
#pragma unroll
            for (int r = 0; r < 4; ++r) {
                float i0 = (float)((double)acc[tt][0][0][r] * 16384.0 + (double)acc[tt][1][0][r] * 8.0);
                i0 = __fadd_rn(i0, b2v0);
                float rst0 = (m2a[r] > 1.0f) ? 1.0f : 0.0f;
                m2a[r] = __fmul_rn(0.9f, m2a[r]);
                m2a[r] = __fadd_rn(m2a[r], i0);
                m2a[r] = __fsub_rn(m2a[r], rst0);
                float i1 = (float)((double)acc[tt][0][1][r] * 16384.0 + (double)acc[tt][1][1][r] * 8.0);
                i1 = __fadd_rn(i1, b2v1);
                float rst1 = (m2b[r] > 1.0f) ? 1.0f : 0.0f;
                m2b[r] = __fmul_rn(0.9f, m2b[r]);
                m2b[r] = __fadd_rn(m2b[r], i1);
                m2b[r] = __fsub_rn(m2b[r], rst1);
                double pv = ((m2a[r] > 1.0f) ? wov0 : 0.0) + ((m2b[r] > 1.0f) ? wov1 : 0.0);
                pv += __shfl_xor(pv, 1);
                pv += __shfl_xor(pv, 2);
                pv += __shfl_xor(pv, 4);
                pv += __shfl_xor(pv, 8);
                if (l15 == r)
                    po[(size_t)((5 + tt) * 32 + jblk) * BSZ + rowb + r] = (float)pv;
            }
        }
    }
}

// k3: sum 32 partials (ascending j-blocks), fp32-replica LIF-out, mean.
__global__ void k3_out(const float* __restrict__ po, const float* __restrict__ bo,
                       float* __restrict__ out) {
    int b = blockIdx.x * 256 + threadIdx.x;
    float mo = 0.0f, s = 0.0f;
    float bov = bo[0];
    for (int t = 0; t < 10; ++t) {
        float inp = 0.0f;
#pragma unroll
        for (int jb = 0; jb < 32; ++jb) inp += po[(size_t)(t * 32 + jb) * BSZ + b];
        inp = __fadd_rn(inp, bov);
        float rst = (mo > 1.0f) ? 1.0f : 0.0f;
        mo = __fmul_rn(0.9f, mo);
        mo = __fadd_rn(mo, inp);
        mo = __fsub_rn(mo, rst);
        s += mo;
    }
    out[b] = s / 10.0f;
}

extern "C" void kernel_launch(void* const* d_in, const int* in_sizes, int n_in,
                              void* d_out, int out_size, void* d_ws, size_t ws_size,
                              hipStream_t stream) {
    (void)in_sizes; (void)n_in; (void)out_size; (void)ws_size;
    const float* x  = (const float*)d_in[0];
    const float* W1 = (const float*)d_in[1];
    const float* b1 = (const float*)d_in[2];
    const float* W2 = (const float*)d_in[3];
    const float* b2 = (const float*)d_in[4];
    const float* Wo = (const float*)d_in[5];
    const float* bo = (const float*)d_in[6];
    float* out = (float*)d_out;

    char* ws = (char*)d_ws;
    f16* w2d = (f16*)ws;                                                   // 4 MiB @ 0
    unsigned short* s1bits = (unsigned short*)(ws + ((size_t)16 << 20));   // 128 MiB
    float* po = (float*)(ws + ((size_t)160 << 20));                        // 80 MiB

    prep_dekker<<<dim3((H * H) / 256), 256, 0, stream>>>(W2, w2d);
    k1_chain<<<dim3(4, BSZ / 64), 256, 0, stream>>>(x, W1, b1, s1bits);
    k2_spikes_gemm<<<dim3(H / 32, BSZ / 64), 512, 0, stream>>>(s1bits, w2d, b2, Wo, po);
    k3_out<<<dim3(BSZ / 256), 256, 0, stream>>>(po, bo, out);
}